// Round 22
// baseline (115.024 us; speedup 1.0000x reference)
//
#include <hip/hip_runtime.h>
#include <hip/hip_bf16.h>

#define BB 4
#define LL 512
#define NTYPES 20
#define HH 6
#define DKK 10
#define DMM 60
#define PROW 516        // residue-major padded row: 3 regions x 172
#define NWROW 516       // W row padding (slot = (j%3)*172 + j/3)

// ---------------- helpers ----------------
__device__ __forceinline__ float softplus_fast(float x) {
    return fmaxf(x, 0.0f) + __logf(1.0f + __expf(-fabsf(x)));
}

// ---------------- kernel A: feat -> q, kR, vR (row-major, coalesced) + W ----------------
// ATTRIBUTION PROBE: grid x9, pos = blockIdx & 2047 -> copies rewrite identical
// values (pure function of ev/emb/weights; race-free; output unchanged).
// qkv_exec = (dur - 57.8)/8; if >=6us it enters top-5 with true counters.
__global__ void ishp_qkv(const float* __restrict__ ev,
                         const float* __restrict__ embed_w,
                         const float* __restrict__ qw, const float* __restrict__ qb,
                         const float* __restrict__ kw, const float* __restrict__ kb,
                         const float* __restrict__ vw, const float* __restrict__ vb,
                         const float* __restrict__ aw, const float* __restrict__ gw,
                         float* __restrict__ q, float* __restrict__ kR, float* __restrict__ vR,
                         float* __restrict__ Wbuf)
{
    int pos = blockIdx.x & 2047;     // b*L + l (9 identical copies)
    int b = pos >> 9, l = pos & 511;
    __shared__ float feat[DMM];
    __shared__ float sv[DMM];
    int t = threadIdx.x;
    if (t == 0) {
        float t1 = ev[(b * (LL + 1) + l) * 2 + 0];
        float t0 = (l > 0) ? ev[(b * (LL + 1) + l - 1) * 2 + 0] : 0.0f;
        feat[0] = t1 - t0;
    } else if (t < DMM) {
        int type = (int)ev[(b * (LL + 1) + l) * 2 + 1];
        feat[t] = embed_w[(t - 1) * NTYPES + type];
    }
    __syncthreads();
    if (t < 3 * DMM) {
        int which = t / DMM;
        int m = t - which * DMM;
        const float* w  = which == 0 ? qw : which == 1 ? kw : vw;
        const float* bs = which == 0 ? qb : which == 1 ? kb : vb;
        float s = bs[m];
        #pragma unroll
        for (int c = 0; c < DMM; ++c) s += feat[c] * w[m * DMM + c];
        int h = m / DKK, d = m - h * DKK;
        size_t off = ((size_t)(b * HH + h) * LL + l) * DKK + d;
        if (which == 0)      q [off] = s;
        else if (which == 1) kR[off] = s;
        else {
            vR[off] = s;
            sv[m] = s;
        }
    }
    __syncthreads();
    if (t < 180) {
        int kk = t % 10;
        int u = t / 10;            // 0..17
        int h  = u % 3;
        int cc = (u / 3) % 3;
        int mat = u / 9;           // 0 = alpha, 1 = gamma
        const float* w = mat ? gw : aw;
        float s = 0.0f;
        #pragma unroll
        for (int d = 0; d < DKK; ++d) s += w[kk * 30 + cc * 10 + d] * sv[(h + 3 * mat) * DKK + d];
        int slot = (l % 3) * 172 + l / 3;
        Wbuf[((size_t)((((mat * 3 + cc) * 4 + b) * 3 + h) * 10 + kk)) * NWROW + slot] = s;
    }
}

// ---------------- kernel B: attention, K/V staged to LDS (40960 B) ----------------
__global__ __launch_bounds__(256) void ishp_attn(const float* __restrict__ q,
                                                 const float* __restrict__ kR,
                                                 const float* __restrict__ vR,
                                                 __hip_bfloat16* __restrict__ pbuf,
                                                 float* __restrict__ vmupre)
{
    __shared__ float sK[DKK * LL];   // [d][512]
    __shared__ float sV[DKK * LL];
    int bh = blockIdx.x >> 5;
    int rg = blockIdx.x & 31;
    int tid = threadIdx.x;
    int lane = tid & 63;
    int wv = tid >> 6;

    const float2* k2 = reinterpret_cast<const float2*>(kR + (size_t)bh * DKK * LL);
    const float2* v2 = reinterpret_cast<const float2*>(vR + (size_t)bh * DKK * LL);
    #pragma unroll
    for (int u = 0; u < 10; ++u) {
        int idx = u * 256 + tid;        // 0..2559
        int l = idx / 5, dp = idx % 5;
        float2 kv = k2[idx];
        sK[(2 * dp) * LL + l] = kv.x;
        sK[(2 * dp + 1) * LL + l] = kv.y;
        float2 vv = v2[idx];
        sV[(2 * dp) * LL + l] = vv.x;
        sV[(2 * dp + 1) * LL + l] = vv.y;
    }
    __syncthreads();

    const float scale = 0.31622776601683794f; // 1/sqrt(10)

    #pragma unroll
    for (int sidx = 0; sidx < 2; ++sidx) {
        int P = rg * 8 + wv + 4 * sidx;     // pair id 0..255
        #pragma unroll
        for (int half = 0; half < 2; ++half) {
            int i = half == 0 ? (511 - P) : P;
            float qr[DKK];
            #pragma unroll
            for (int d = 0; d < DKK; ++d) qr[d] = q[((size_t)bh * LL + i) * DKK + d];
            int nchunk = (i >> 6) + 1;

            float e[8];
            float S = 0.0f;
            #pragma unroll
            for (int c = 0; c < 8; ++c) {
                e[c] = 0.0f;
                if (c < nchunk) {
                    int j = c * 64 + lane;
                    float dot = 0.0f;
                    #pragma unroll
                    for (int d = 0; d < DKK; ++d) dot += qr[d] * sK[d * LL + j];
                    if (j <= i) e[c] = __expf(dot * scale);
                    S += e[c];
                }
            }
            #pragma unroll
            for (int off = 32; off >= 1; off >>= 1) S += __shfl_xor(S, off, 64);
            float inv = 1.0f / S;

            __hip_bfloat16* prow = pbuf + (size_t)(bh * LL + i) * PROW;
            #pragma unroll
            for (int c = 0; c < 8; ++c) {
                if (c < nchunk) {
                    int j = c * 64 + lane;
                    int slot = (j % 3) * 172 + j / 3;
                    if (j <= i) prow[slot] = __float2bfloat16(e[c] * inv);
                }
            }

            float acc[DKK];
            #pragma unroll
            for (int d = 0; d < DKK; ++d) acc[d] = 0.0f;
            #pragma unroll
            for (int c = 0; c < 8; ++c) {
                if (c < nchunk) {
                    int j = c * 64 + lane;
                    #pragma unroll
                    for (int d = 0; d < DKK; ++d) acc[d] += e[c] * sV[d * LL + j];
                }
            }
            #pragma unroll
            for (int d = 0; d < DKK; ++d) {
                float a = acc[d];
                #pragma unroll
                for (int off = 32; off >= 1; off >>= 1) a += __shfl_xor(a, off, 64);
                acc[d] = a;
            }
            if (lane == 0) {
                #pragma unroll
                for (int d = 0; d < DKK; ++d)
                    vmupre[((size_t)bh * LL + i) * DKK + d] = acc[d] * inv;
            }
        }
    }
}

// ---------------- kernel C: v_alpha / v_gamma (+fused v_mu) ----------------
__global__ __launch_bounds__(256) void ishp_ag(const __hip_bfloat16* __restrict__ pbuf,
                                               const float* __restrict__ Wbuf,
                                               const float* __restrict__ ab,
                                               const float* __restrict__ gb,
                                               const float* __restrict__ vmupre,
                                               const float* __restrict__ muw,
                                               const float* __restrict__ mub,
                                               float* __restrict__ out_mu,
                                               float* __restrict__ outA,
                                               float* __restrict__ outG)
{
    __shared__ float sA[2560];
    __shared__ float sG[2560];
    int tid = threadIdx.x;
    int pos = blockIdx.x * 256 + tid;
    int b  = pos >> 18;
    int i2 = (pos >> 9) & 511;
    int j2 = pos & 511;

    float ra[DKK], rg[DKK];
    if (j2 > i2) {
        #pragma unroll
        for (int kk = 0; kk < DKK; ++kk) { ra[kk] = 0.0f; rg[kk] = 0.0f; }
    } else {
        #pragma unroll
        for (int kk = 0; kk < DKK; ++kk) { ra[kk] = ab[kk]; rg[kk] = gb[kk]; }
        #pragma unroll
        for (int cc = 0; cc < 3; ++cc) {
            int u = 3 * j2 + cc;
            int sel = u >> 9;
            int j = u & 511;
            int hi = 3 * i2 + sel;
            int h = hi >> 9;
            int i = hi & 511;
            int jq = j / 3;
            int r = j - 3 * jq;
            int slot = r * 172 + jq;
            float pa = 0.0f, pg = 0.0f;
            if (j <= i) {
                pa = __bfloat162float(pbuf[(size_t)((b * HH + h) * LL + i) * PROW + slot]);
                pg = __bfloat162float(pbuf[(size_t)((b * HH + h + 3) * LL + i) * PROW + slot]);
            }
            const float* Wa = Wbuf + ((size_t)(((0 + cc) * 4 + b) * 3 + h) * 10) * NWROW + slot;
            const float* Wg = Wbuf + ((size_t)(((3 + cc) * 4 + b) * 3 + h) * 10) * NWROW + slot;
            #pragma unroll
            for (int kk = 0; kk < DKK; ++kk) {
                ra[kk] += pa * Wa[kk * NWROW];
                rg[kk] += pg * Wg[kk * NWROW];
            }
        }
        #pragma unroll
        for (int kk = 0; kk < DKK; ++kk) {
            ra[kk] = softplus_fast(ra[kk]);
            rg[kk] = softplus_fast(10.0f * rg[kk]) * 0.1f;
        }
    }
    #pragma unroll
    for (int kk = 0; kk < DKK; ++kk) { sA[tid * 10 + kk] = ra[kk]; sG[tid * 10 + kk] = rg[kk]; }
    __syncthreads();

    size_t base = (size_t)blockIdx.x * 2560;
    #pragma unroll
    for (int it = 0; it < 3; ++it) {
        int idx = it * 1024 + tid * 4;
        if (idx < 2560) {
            *reinterpret_cast<float4*>(outA + base + idx) = *reinterpret_cast<const float4*>(&sA[idx]);
            *reinterpret_cast<float4*>(outG + base + idx) = *reinterpret_cast<const float4*>(&sG[idx]);
        }
    }

    if (blockIdx.x < 8) {
        int mpos = blockIdx.x * 256 + tid;    // b*L + l
        int mb = mpos >> 9, ml = mpos & 511;
        float y[DKK];
        #pragma unroll
        for (int kk = 0; kk < DKK; ++kk) y[kk] = mub[kk];
        for (int c = 0; c < DMM; ++c) {
            int h = c / DKK, d = c - h * DKK;
            float xc = vmupre[((mb * HH + h) * LL + ml) * DKK + d];
            #pragma unroll
            for (int kk = 0; kk < DKK; ++kk) y[kk] += xc * muw[kk * DMM + c];
        }
        #pragma unroll
        for (int kk = 0; kk < DKK; ++kk)
            out_mu[(size_t)mpos * DKK + kk] = 1.0f / (1.0f + __expf(-y[kk]));
    }
}

// ---------------- launch ----------------
extern "C" void kernel_launch(void* const* d_in, const int* in_sizes, int n_in,
                              void* d_out, int out_size, void* d_ws, size_t ws_size,
                              hipStream_t stream) {
    const void *ev = 0, *emb = 0, *muw = 0;
    const void *w3[3] = {0, 0, 0}, *b3[3] = {0, 0, 0};
    const void *w300[2] = {0, 0};
    const void *b10[3] = {0, 0, 0};
    int n3 = 0, nb3 = 0, n300 = 0, n10 = 0;
    for (int i = 0; i < n_in; ++i) {
        int s = in_sizes[i];
        if      (s == 4104) ev  = d_in[i];
        else if (s == 1180) emb = d_in[i];
        else if (s == 600)  muw = d_in[i];
        else if (s == 3600) { if (n3  < 3) w3[n3++]   = d_in[i]; }
        else if (s == 60)   { if (nb3 < 3) b3[nb3++]  = d_in[i]; }
        else if (s == 300)  { if (n300< 2) w300[n300++]=d_in[i]; }
        else if (s == 10)   { if (n10 < 3) b10[n10++] = d_in[i]; }
    }

    float* ws = (float*)d_ws;
    float* q = ws;
    float* kR = q + 122880;
    float* vR = kR + 122880;
    float* vmupre = vR + 122880;
    float* Wbuf = vmupre + 122880;
    __hip_bfloat16* pbuf = (__hip_bfloat16*)(Wbuf + 371520);

    float* out = (float*)d_out;
    float* out_mu = out;
    float* out_a  = out + 20480;
    float* out_g  = out + 20480 + 10485760;

    // PROBE: grid x9 (2048 real blocks replicated; & 2047 inside)
    ishp_qkv<<<9 * BB * LL, 192, 0, stream>>>((const float*)ev, (const float*)emb,
        (const float*)w3[0], (const float*)b3[0],
        (const float*)w3[1], (const float*)b3[1],
        (const float*)w3[2], (const float*)b3[2],
        (const float*)w300[0], (const float*)w300[1],
        q, kR, vR, Wbuf);
    ishp_attn<<<BB * HH * 32, 256, 0, stream>>>(q, kR, vR, pbuf, vmupre);
    ishp_ag<<<(BB * LL * LL) / 256, 256, 0, stream>>>(pbuf, Wbuf,
        (const float*)b10[0], (const float*)b10[1], vmupre,
        (const float*)muw, (const float*)b10[2], out_mu, out_a, out_g);
}

// Round 23
// 56.084 us; speedup vs baseline: 2.0509x; 2.0509x over previous
//
#include <hip/hip_runtime.h>
#include <hip/hip_bf16.h>

#define BB 4
#define LL 512
#define NTYPES 20
#define HH 6
#define DKK 10
#define DMM 60
#define PROW 516        // residue-major padded row: 3 regions x 172
#define NWROW 516       // W row padding (slot = (j%3)*172 + j/3)

// ---------------- helpers ----------------
__device__ __forceinline__ float softplus_fast(float x) {
    return fmaxf(x, 0.0f) + __logf(1.0f + __expf(-fabsf(x)));
}

// ---------------- kernel A: feat -> q, kR, vR + W; 8 positions per block ----------------
// 256 blocks x 256 threads. Weight rows hoisted to VGPRs, reused 8x.
// Dot order (c ascending from bias) and store addresses identical to R19 -> bit-identical.
__global__ __launch_bounds__(256) void ishp_qkv(
        const float* __restrict__ ev, const float* __restrict__ embed_w,
        const float* __restrict__ qw, const float* __restrict__ qb,
        const float* __restrict__ kw, const float* __restrict__ kb,
        const float* __restrict__ vw, const float* __restrict__ vb,
        const float* __restrict__ aw, const float* __restrict__ gw,
        float* __restrict__ q, float* __restrict__ kR, float* __restrict__ vR,
        float* __restrict__ Wbuf)
{
    int blk = blockIdx.x;            // 256 blocks; positions blk*8 .. blk*8+7
    int b = blk >> 6;
    int l0 = (blk & 63) * 8;
    __shared__ float sFeat[8][61];
    __shared__ float sv8[8][DMM];
    __shared__ int   sTyp[8];
    int t = threadIdx.x;

    if (t < 8) {
        int l = l0 + t;
        float t1 = ev[(b * (LL + 1) + l) * 2 + 0];
        float t0 = (l > 0) ? ev[(b * (LL + 1) + l - 1) * 2 + 0] : 0.0f;
        sFeat[t][0] = t1 - t0;
        sTyp[t] = (int)ev[(b * (LL + 1) + l) * 2 + 1];
    }
    __syncthreads();
    #pragma unroll
    for (int u = 0; u < 2; ++u) {
        int idx = u * 256 + t;
        if (idx < 472) {
            int l = idx / 59, c = idx - (idx / 59) * 59;
            sFeat[l][1 + c] = embed_w[c * NTYPES + sTyp[l]];
        }
    }
    __syncthreads();

    if (t < 180) {
        int which = t / DMM;
        int m = t - which * DMM;
        const float* w  = which == 0 ? qw : which == 1 ? kw : vw;
        const float* bs = which == 0 ? qb : which == 1 ? kb : vb;
        float bias = bs[m];
        float wr[DMM];
        #pragma unroll
        for (int c = 0; c < DMM; ++c) wr[c] = w[m * DMM + c];
        int h = m / DKK, d = m - h * DKK;
        #pragma unroll
        for (int s = 0; s < 8; ++s) {
            float acc = bias;
            #pragma unroll
            for (int c = 0; c < DMM; ++c) acc += sFeat[s][c] * wr[c];
            int l = l0 + s;
            size_t off = ((size_t)(b * HH + h) * LL + l) * DKK + d;
            if (which == 0)      q [off] = acc;
            else if (which == 1) kR[off] = acc;
            else { vR[off] = acc; sv8[s][m] = acc; }
        }
    }
    __syncthreads();

    if (t < 180) {
        int kk = t % 10;
        int u = t / 10;            // 0..17
        int h  = u % 3;
        int cc = (u / 3) % 3;
        int mat = u / 9;           // 0 = alpha, 1 = gamma
        const float* w = mat ? gw : aw;
        float wr[DKK];
        #pragma unroll
        for (int d = 0; d < DKK; ++d) wr[d] = w[kk * 30 + cc * 10 + d];
        size_t rowbase = ((size_t)((((mat * 3 + cc) * 4 + b) * 3 + h) * 10 + kk)) * NWROW;
        #pragma unroll
        for (int s = 0; s < 8; ++s) {
            float acc = 0.0f;
            #pragma unroll
            for (int d = 0; d < DKK; ++d) acc += wr[d] * sv8[s][(h + 3 * mat) * DKK + d];
            int l = l0 + s;
            int slot = (l % 3) * 172 + l / 3;
            Wbuf[rowbase + slot] = acc;
        }
    }
}

// ---------------- kernel B: attention, K/V staged to LDS (40960 B) ----------------
__global__ __launch_bounds__(256) void ishp_attn(const float* __restrict__ q,
                                                 const float* __restrict__ kR,
                                                 const float* __restrict__ vR,
                                                 __hip_bfloat16* __restrict__ pbuf,
                                                 float* __restrict__ vmupre)
{
    __shared__ float sK[DKK * LL];   // [d][512]
    __shared__ float sV[DKK * LL];
    int bh = blockIdx.x >> 5;
    int rg = blockIdx.x & 31;
    int tid = threadIdx.x;
    int lane = tid & 63;
    int wv = tid >> 6;

    const float2* k2 = reinterpret_cast<const float2*>(kR + (size_t)bh * DKK * LL);
    const float2* v2 = reinterpret_cast<const float2*>(vR + (size_t)bh * DKK * LL);
    #pragma unroll
    for (int u = 0; u < 10; ++u) {
        int idx = u * 256 + tid;        // 0..2559
        int l = idx / 5, dp = idx % 5;
        float2 kv = k2[idx];
        sK[(2 * dp) * LL + l] = kv.x;
        sK[(2 * dp + 1) * LL + l] = kv.y;
        float2 vv = v2[idx];
        sV[(2 * dp) * LL + l] = vv.x;
        sV[(2 * dp + 1) * LL + l] = vv.y;
    }
    __syncthreads();

    const float scale = 0.31622776601683794f; // 1/sqrt(10)

    #pragma unroll
    for (int sidx = 0; sidx < 2; ++sidx) {
        int P = rg * 8 + wv + 4 * sidx;     // pair id 0..255
        #pragma unroll
        for (int half = 0; half < 2; ++half) {
            int i = half == 0 ? (511 - P) : P;
            float qr[DKK];
            #pragma unroll
            for (int d = 0; d < DKK; ++d) qr[d] = q[((size_t)bh * LL + i) * DKK + d];
            int nchunk = (i >> 6) + 1;

            float e[8];
            float S = 0.0f;
            #pragma unroll
            for (int c = 0; c < 8; ++c) {
                e[c] = 0.0f;
                if (c < nchunk) {
                    int j = c * 64 + lane;
                    float dot = 0.0f;
                    #pragma unroll
                    for (int d = 0; d < DKK; ++d) dot += qr[d] * sK[d * LL + j];
                    if (j <= i) e[c] = __expf(dot * scale);
                    S += e[c];
                }
            }
            #pragma unroll
            for (int off = 32; off >= 1; off >>= 1) S += __shfl_xor(S, off, 64);
            float inv = 1.0f / S;

            __hip_bfloat16* prow = pbuf + (size_t)(bh * LL + i) * PROW;
            #pragma unroll
            for (int c = 0; c < 8; ++c) {
                if (c < nchunk) {
                    int j = c * 64 + lane;
                    int slot = (j % 3) * 172 + j / 3;
                    if (j <= i) prow[slot] = __float2bfloat16(e[c] * inv);
                }
            }

            float acc[DKK];
            #pragma unroll
            for (int d = 0; d < DKK; ++d) acc[d] = 0.0f;
            #pragma unroll
            for (int c = 0; c < 8; ++c) {
                if (c < nchunk) {
                    int j = c * 64 + lane;
                    #pragma unroll
                    for (int d = 0; d < DKK; ++d) acc[d] += e[c] * sV[d * LL + j];
                }
            }
            #pragma unroll
            for (int d = 0; d < DKK; ++d) {
                float a = acc[d];
                #pragma unroll
                for (int off = 32; off >= 1; off >>= 1) a += __shfl_xor(a, off, 64);
                acc[d] = a;
            }
            if (lane == 0) {
                #pragma unroll
                for (int d = 0; d < DKK; ++d)
                    vmupre[((size_t)bh * LL + i) * DKK + d] = acc[d] * inv;
            }
        }
    }
}

// ---------------- kernel C: v_alpha / v_gamma (+fused v_mu) ----------------
__global__ __launch_bounds__(256) void ishp_ag(const __hip_bfloat16* __restrict__ pbuf,
                                               const float* __restrict__ Wbuf,
                                               const float* __restrict__ ab,
                                               const float* __restrict__ gb,
                                               const float* __restrict__ vmupre,
                                               const float* __restrict__ muw,
                                               const float* __restrict__ mub,
                                               float* __restrict__ out_mu,
                                               float* __restrict__ outA,
                                               float* __restrict__ outG)
{
    __shared__ float sA[2560];
    __shared__ float sG[2560];
    int tid = threadIdx.x;
    int pos = blockIdx.x * 256 + tid;
    int b  = pos >> 18;
    int i2 = (pos >> 9) & 511;
    int j2 = pos & 511;

    float ra[DKK], rg[DKK];
    if (j2 > i2) {
        #pragma unroll
        for (int kk = 0; kk < DKK; ++kk) { ra[kk] = 0.0f; rg[kk] = 0.0f; }
    } else {
        #pragma unroll
        for (int kk = 0; kk < DKK; ++kk) { ra[kk] = ab[kk]; rg[kk] = gb[kk]; }
        #pragma unroll
        for (int cc = 0; cc < 3; ++cc) {
            int u = 3 * j2 + cc;
            int sel = u >> 9;
            int j = u & 511;
            int hi = 3 * i2 + sel;
            int h = hi >> 9;
            int i = hi & 511;
            int jq = j / 3;
            int r = j - 3 * jq;
            int slot = r * 172 + jq;
            float pa = 0.0f, pg = 0.0f;
            if (j <= i) {
                pa = __bfloat162float(pbuf[(size_t)((b * HH + h) * LL + i) * PROW + slot]);
                pg = __bfloat162float(pbuf[(size_t)((b * HH + h + 3) * LL + i) * PROW + slot]);
            }
            const float* Wa = Wbuf + ((size_t)(((0 + cc) * 4 + b) * 3 + h) * 10) * NWROW + slot;
            const float* Wg = Wbuf + ((size_t)(((3 + cc) * 4 + b) * 3 + h) * 10) * NWROW + slot;
            #pragma unroll
            for (int kk = 0; kk < DKK; ++kk) {
                ra[kk] += pa * Wa[kk * NWROW];
                rg[kk] += pg * Wg[kk * NWROW];
            }
        }
        #pragma unroll
        for (int kk = 0; kk < DKK; ++kk) {
            ra[kk] = softplus_fast(ra[kk]);
            rg[kk] = softplus_fast(10.0f * rg[kk]) * 0.1f;
        }
    }
    #pragma unroll
    for (int kk = 0; kk < DKK; ++kk) { sA[tid * 10 + kk] = ra[kk]; sG[tid * 10 + kk] = rg[kk]; }
    __syncthreads();

    size_t base = (size_t)blockIdx.x * 2560;
    #pragma unroll
    for (int it = 0; it < 3; ++it) {
        int idx = it * 1024 + tid * 4;
        if (idx < 2560) {
            *reinterpret_cast<float4*>(outA + base + idx) = *reinterpret_cast<const float4*>(&sA[idx]);
            *reinterpret_cast<float4*>(outG + base + idx) = *reinterpret_cast<const float4*>(&sG[idx]);
        }
    }

    if (blockIdx.x < 8) {
        int mpos = blockIdx.x * 256 + tid;    // b*L + l
        int mb = mpos >> 9, ml = mpos & 511;
        float y[DKK];
        #pragma unroll
        for (int kk = 0; kk < DKK; ++kk) y[kk] = mub[kk];
        for (int c = 0; c < DMM; ++c) {
            int h = c / DKK, d = c - h * DKK;
            float xc = vmupre[((mb * HH + h) * LL + ml) * DKK + d];
            #pragma unroll
            for (int kk = 0; kk < DKK; ++kk) y[kk] += xc * muw[kk * DMM + c];
        }
        #pragma unroll
        for (int kk = 0; kk < DKK; ++kk)
            out_mu[(size_t)mpos * DKK + kk] = 1.0f / (1.0f + __expf(-y[kk]));
    }
}

// ---------------- launch ----------------
extern "C" void kernel_launch(void* const* d_in, const int* in_sizes, int n_in,
                              void* d_out, int out_size, void* d_ws, size_t ws_size,
                              hipStream_t stream) {
    const void *ev = 0, *emb = 0, *muw = 0;
    const void *w3[3] = {0, 0, 0}, *b3[3] = {0, 0, 0};
    const void *w300[2] = {0, 0};
    const void *b10[3] = {0, 0, 0};
    int n3 = 0, nb3 = 0, n300 = 0, n10 = 0;
    for (int i = 0; i < n_in; ++i) {
        int s = in_sizes[i];
        if      (s == 4104) ev  = d_in[i];
        else if (s == 1180) emb = d_in[i];
        else if (s == 600)  muw = d_in[i];
        else if (s == 3600) { if (n3  < 3) w3[n3++]   = d_in[i]; }
        else if (s == 60)   { if (nb3 < 3) b3[nb3++]  = d_in[i]; }
        else if (s == 300)  { if (n300< 2) w300[n300++]=d_in[i]; }
        else if (s == 10)   { if (n10 < 3) b10[n10++] = d_in[i]; }
    }

    float* ws = (float*)d_ws;
    float* q = ws;
    float* kR = q + 122880;
    float* vR = kR + 122880;
    float* vmupre = vR + 122880;
    float* Wbuf = vmupre + 122880;
    __hip_bfloat16* pbuf = (__hip_bfloat16*)(Wbuf + 371520);

    float* out = (float*)d_out;
    float* out_mu = out;
    float* out_a  = out + 20480;
    float* out_g  = out + 20480 + 10485760;

    ishp_qkv<<<(BB * LL) / 8, 256, 0, stream>>>((const float*)ev, (const float*)emb,
        (const float*)w3[0], (const float*)b3[0],
        (const float*)w3[1], (const float*)b3[1],
        (const float*)w3[2], (const float*)b3[2],
        (const float*)w300[0], (const float*)w300[1],
        q, kR, vR, Wbuf);
    ishp_attn<<<BB * HH * 32, 256, 0, stream>>>(q, kR, vR, pbuf, vmupre);
    ishp_ag<<<(BB * LL * LL) / 256, 256, 0, stream>>>(pbuf, Wbuf,
        (const float*)b10[0], (const float*)b10[1], vmupre,
        (const float*)muw, (const float*)b10[2], out_mu, out_a, out_g);
}

// Round 24
// 53.196 us; speedup vs baseline: 2.1623x; 1.0543x over previous
//
#include <hip/hip_runtime.h>
#include <hip/hip_bf16.h>

#define BB 4
#define LL 512
#define NTYPES 20
#define HH 6
#define DKK 10
#define DMM 60
#define PROW 516        // residue-major padded row: 3 regions x 172
#define NWROW 516       // W row padding (slot = (j%3)*172 + j/3)
#define KROW 12         // padded LDS row: 48 B -> b128-aligned, conflict-optimal

// ---------------- helpers ----------------
__device__ __forceinline__ float softplus_fast(float x) {
    return fmaxf(x, 0.0f) + __logf(1.0f + __expf(-fabsf(x)));
}

// ---------------- kernel A: feat -> q, kR, vR + W; 8 positions per block ----------------
__global__ __launch_bounds__(256) void ishp_qkv(
        const float* __restrict__ ev, const float* __restrict__ embed_w,
        const float* __restrict__ qw, const float* __restrict__ qb,
        const float* __restrict__ kw, const float* __restrict__ kb,
        const float* __restrict__ vw, const float* __restrict__ vb,
        const float* __restrict__ aw, const float* __restrict__ gw,
        float* __restrict__ q, float* __restrict__ kR, float* __restrict__ vR,
        float* __restrict__ Wbuf)
{
    int blk = blockIdx.x;            // 256 blocks; positions blk*8 .. blk*8+7
    int b = blk >> 6;
    int l0 = (blk & 63) * 8;
    __shared__ float sFeat[8][61];
    __shared__ float sv8[8][DMM];
    __shared__ int   sTyp[8];
    int t = threadIdx.x;

    if (t < 8) {
        int l = l0 + t;
        float t1 = ev[(b * (LL + 1) + l) * 2 + 0];
        float t0 = (l > 0) ? ev[(b * (LL + 1) + l - 1) * 2 + 0] : 0.0f;
        sFeat[t][0] = t1 - t0;
        sTyp[t] = (int)ev[(b * (LL + 1) + l) * 2 + 1];
    }
    __syncthreads();
    #pragma unroll
    for (int u = 0; u < 2; ++u) {
        int idx = u * 256 + t;
        if (idx < 472) {
            int l = idx / 59, c = idx - (idx / 59) * 59;
            sFeat[l][1 + c] = embed_w[c * NTYPES + sTyp[l]];
        }
    }
    __syncthreads();

    if (t < 180) {
        int which = t / DMM;
        int m = t - which * DMM;
        const float* w  = which == 0 ? qw : which == 1 ? kw : vw;
        const float* bs = which == 0 ? qb : which == 1 ? kb : vb;
        float bias = bs[m];
        float wr[DMM];
        #pragma unroll
        for (int c = 0; c < DMM; ++c) wr[c] = w[m * DMM + c];
        int h = m / DKK, d = m - h * DKK;
        #pragma unroll
        for (int s = 0; s < 8; ++s) {
            float acc = bias;
            #pragma unroll
            for (int c = 0; c < DMM; ++c) acc += sFeat[s][c] * wr[c];
            int l = l0 + s;
            size_t off = ((size_t)(b * HH + h) * LL + l) * DKK + d;
            if (which == 0)      q [off] = acc;
            else if (which == 1) kR[off] = acc;
            else { vR[off] = acc; sv8[s][m] = acc; }
        }
    }
    __syncthreads();

    if (t < 180) {
        int kk = t % 10;
        int u = t / 10;            // 0..17
        int h  = u % 3;
        int cc = (u / 3) % 3;
        int mat = u / 9;           // 0 = alpha, 1 = gamma
        const float* w = mat ? gw : aw;
        float wr[DKK];
        #pragma unroll
        for (int d = 0; d < DKK; ++d) wr[d] = w[kk * 30 + cc * 10 + d];
        size_t rowbase = ((size_t)((((mat * 3 + cc) * 4 + b) * 3 + h) * 10 + kk)) * NWROW;
        #pragma unroll
        for (int s = 0; s < 8; ++s) {
            float acc = 0.0f;
            #pragma unroll
            for (int d = 0; d < DKK; ++d) acc += wr[d] * sv8[s][(h + 3 * mat) * DKK + d];
            int l = l0 + s;
            int slot = (l % 3) * 172 + l / 3;
            Wbuf[rowbase + slot] = acc;
        }
    }
}

// ---------------- kernel B: attention; LDS [j][12] rows, vector reads, joint pairs ----------------
__global__ __launch_bounds__(256) void ishp_attn(const float* __restrict__ q,
                                                 const float* __restrict__ kR,
                                                 const float* __restrict__ vR,
                                                 __hip_bfloat16* __restrict__ pbuf,
                                                 float* __restrict__ vmupre)
{
    __shared__ float sK[LL * KROW];   // [j][12], 24576 B
    __shared__ float sV[LL * KROW];
    int bh = blockIdx.x >> 5;
    int rg = blockIdx.x & 31;
    int tid = threadIdx.x;
    int lane = tid & 63;
    int wv = tid >> 6;

    // stage: row-major [l][10] -> LDS [l][12] via float2
    const float2* k2 = reinterpret_cast<const float2*>(kR + (size_t)bh * DKK * LL);
    const float2* v2 = reinterpret_cast<const float2*>(vR + (size_t)bh * DKK * LL);
    #pragma unroll
    for (int u = 0; u < 10; ++u) {
        int idx = u * 256 + tid;        // 0..2559
        int l = idx / 5, dp = idx - (idx / 5) * 5;
        float2 kv = k2[idx];
        sK[l * KROW + 2 * dp]     = kv.x;
        sK[l * KROW + 2 * dp + 1] = kv.y;
        float2 vv = v2[idx];
        sV[l * KROW + 2 * dp]     = vv.x;
        sV[l * KROW + 2 * dp + 1] = vv.y;
    }
    __syncthreads();

    const float scale = 0.31622776601683794f; // 1/sqrt(10)

    #pragma unroll
    for (int sidx = 0; sidx < 2; ++sidx) {
        int P = rg * 8 + wv + 4 * sidx;     // pair id 0..255
        int i_hi = 511 - P, i_lo = P;
        float qh[DKK], ql[DKK];
        #pragma unroll
        for (int d = 0; d < DKK; ++d) {
            qh[d] = q[((size_t)bh * LL + i_hi) * DKK + d];
            ql[d] = q[((size_t)bh * LL + i_lo) * DKK + d];
        }
        int nch_h = (i_hi >> 6) + 1;        // 5..8
        int nch_l = (i_lo >> 6) + 1;        // 1..4

        float eh[8], el[8];
        float Sh = 0.0f, Sl = 0.0f;
        #pragma unroll
        for (int c = 0; c < 8; ++c) {
            eh[c] = 0.0f; el[c] = 0.0f;
            if (c < nch_h) {
                int j = c * 64 + lane;
                const float* kr = &sK[j * KROW];
                float4 k0 = *reinterpret_cast<const float4*>(kr);
                float4 k1 = *reinterpret_cast<const float4*>(kr + 4);
                float2 kv2 = *reinterpret_cast<const float2*>(kr + 8);
                float dh = qh[0] * k0.x; dh += qh[1] * k0.y; dh += qh[2] * k0.z; dh += qh[3] * k0.w;
                dh += qh[4] * k1.x; dh += qh[5] * k1.y; dh += qh[6] * k1.z; dh += qh[7] * k1.w;
                dh += qh[8] * kv2.x; dh += qh[9] * kv2.y;
                if (j <= i_hi) eh[c] = __expf(dh * scale);
                Sh += eh[c];
                if (c < nch_l) {
                    float dl = ql[0] * k0.x; dl += ql[1] * k0.y; dl += ql[2] * k0.z; dl += ql[3] * k0.w;
                    dl += ql[4] * k1.x; dl += ql[5] * k1.y; dl += ql[6] * k1.z; dl += ql[7] * k1.w;
                    dl += ql[8] * kv2.x; dl += ql[9] * kv2.y;
                    if (j <= i_lo) el[c] = __expf(dl * scale);
                    Sl += el[c];
                }
            }
        }
        #pragma unroll
        for (int off = 32; off >= 1; off >>= 1) {
            Sh += __shfl_xor(Sh, off, 64);
            Sl += __shfl_xor(Sl, off, 64);
        }
        float inv_h = 1.0f / Sh, inv_l = 1.0f / Sl;

        __hip_bfloat16* prow_h = pbuf + (size_t)(bh * LL + i_hi) * PROW;
        __hip_bfloat16* prow_l = pbuf + (size_t)(bh * LL + i_lo) * PROW;
        #pragma unroll
        for (int c = 0; c < 8; ++c) {
            if (c < nch_h) {
                int j = c * 64 + lane;
                int slot = (j % 3) * 172 + j / 3;
                if (j <= i_hi) prow_h[slot] = __float2bfloat16(eh[c] * inv_h);
                if (c < nch_l && j <= i_lo) prow_l[slot] = __float2bfloat16(el[c] * inv_l);
            }
        }

        float ah[DKK], al[DKK];
        #pragma unroll
        for (int d = 0; d < DKK; ++d) { ah[d] = 0.0f; al[d] = 0.0f; }
        #pragma unroll
        for (int c = 0; c < 8; ++c) {
            if (c < nch_h) {
                int j = c * 64 + lane;
                const float* vr = &sV[j * KROW];
                float4 v0 = *reinterpret_cast<const float4*>(vr);
                float4 v1 = *reinterpret_cast<const float4*>(vr + 4);
                float2 vv2 = *reinterpret_cast<const float2*>(vr + 8);
                ah[0] += eh[c] * v0.x; ah[1] += eh[c] * v0.y; ah[2] += eh[c] * v0.z; ah[3] += eh[c] * v0.w;
                ah[4] += eh[c] * v1.x; ah[5] += eh[c] * v1.y; ah[6] += eh[c] * v1.z; ah[7] += eh[c] * v1.w;
                ah[8] += eh[c] * vv2.x; ah[9] += eh[c] * vv2.y;
                if (c < nch_l) {
                    al[0] += el[c] * v0.x; al[1] += el[c] * v0.y; al[2] += el[c] * v0.z; al[3] += el[c] * v0.w;
                    al[4] += el[c] * v1.x; al[5] += el[c] * v1.y; al[6] += el[c] * v1.z; al[7] += el[c] * v1.w;
                    al[8] += el[c] * vv2.x; al[9] += el[c] * vv2.y;
                }
            }
        }
        #pragma unroll
        for (int d = 0; d < DKK; ++d) {
            float a0 = ah[d], a1 = al[d];
            #pragma unroll
            for (int off = 32; off >= 1; off >>= 1) {
                a0 += __shfl_xor(a0, off, 64);
                a1 += __shfl_xor(a1, off, 64);
            }
            ah[d] = a0; al[d] = a1;
        }
        if (lane == 0) {
            #pragma unroll
            for (int d = 0; d < DKK; ++d) {
                vmupre[((size_t)bh * LL + i_hi) * DKK + d] = ah[d] * inv_h;
                vmupre[((size_t)bh * LL + i_lo) * DKK + d] = al[d] * inv_l;
            }
        }
    }
}

// ---------------- kernel C: v_alpha / v_gamma (+fused v_mu) ----------------
__global__ __launch_bounds__(256) void ishp_ag(const __hip_bfloat16* __restrict__ pbuf,
                                               const float* __restrict__ Wbuf,
                                               const float* __restrict__ ab,
                                               const float* __restrict__ gb,
                                               const float* __restrict__ vmupre,
                                               const float* __restrict__ muw,
                                               const float* __restrict__ mub,
                                               float* __restrict__ out_mu,
                                               float* __restrict__ outA,
                                               float* __restrict__ outG)
{
    __shared__ float sA[2560];
    __shared__ float sG[2560];
    int tid = threadIdx.x;
    int pos = blockIdx.x * 256 + tid;
    int b  = pos >> 18;
    int i2 = (pos >> 9) & 511;
    int j2 = pos & 511;

    float ra[DKK], rg[DKK];
    if (j2 > i2) {
        #pragma unroll
        for (int kk = 0; kk < DKK; ++kk) { ra[kk] = 0.0f; rg[kk] = 0.0f; }
    } else {
        #pragma unroll
        for (int kk = 0; kk < DKK; ++kk) { ra[kk] = ab[kk]; rg[kk] = gb[kk]; }
        #pragma unroll
        for (int cc = 0; cc < 3; ++cc) {
            int u = 3 * j2 + cc;
            int sel = u >> 9;
            int j = u & 511;
            int hi = 3 * i2 + sel;
            int h = hi >> 9;
            int i = hi & 511;
            int jq = j / 3;
            int r = j - 3 * jq;
            int slot = r * 172 + jq;
            float pa = 0.0f, pg = 0.0f;
            if (j <= i) {
                pa = __bfloat162float(pbuf[(size_t)((b * HH + h) * LL + i) * PROW + slot]);
                pg = __bfloat162float(pbuf[(size_t)((b * HH + h + 3) * LL + i) * PROW + slot]);
            }
            const float* Wa = Wbuf + ((size_t)(((0 + cc) * 4 + b) * 3 + h) * 10) * NWROW + slot;
            const float* Wg = Wbuf + ((size_t)(((3 + cc) * 4 + b) * 3 + h) * 10) * NWROW + slot;
            #pragma unroll
            for (int kk = 0; kk < DKK; ++kk) {
                ra[kk] += pa * Wa[kk * NWROW];
                rg[kk] += pg * Wg[kk * NWROW];
            }
        }
        #pragma unroll
        for (int kk = 0; kk < DKK; ++kk) {
            ra[kk] = softplus_fast(ra[kk]);
            rg[kk] = softplus_fast(10.0f * rg[kk]) * 0.1f;
        }
    }
    #pragma unroll
    for (int kk = 0; kk < DKK; ++kk) { sA[tid * 10 + kk] = ra[kk]; sG[tid * 10 + kk] = rg[kk]; }
    __syncthreads();

    size_t base = (size_t)blockIdx.x * 2560;
    #pragma unroll
    for (int it = 0; it < 3; ++it) {
        int idx = it * 1024 + tid * 4;
        if (idx < 2560) {
            *reinterpret_cast<float4*>(outA + base + idx) = *reinterpret_cast<const float4*>(&sA[idx]);
            *reinterpret_cast<float4*>(outG + base + idx) = *reinterpret_cast<const float4*>(&sG[idx]);
        }
    }

    if (blockIdx.x < 8) {
        int mpos = blockIdx.x * 256 + tid;    // b*L + l
        int mb = mpos >> 9, ml = mpos & 511;
        float y[DKK];
        #pragma unroll
        for (int kk = 0; kk < DKK; ++kk) y[kk] = mub[kk];
        for (int c = 0; c < DMM; ++c) {
            int h = c / DKK, d = c - h * DKK;
            float xc = vmupre[((mb * HH + h) * LL + ml) * DKK + d];
            #pragma unroll
            for (int kk = 0; kk < DKK; ++kk) y[kk] += xc * muw[kk * DMM + c];
        }
        #pragma unroll
        for (int kk = 0; kk < DKK; ++kk)
            out_mu[(size_t)mpos * DKK + kk] = 1.0f / (1.0f + __expf(-y[kk]));
    }
}

// ---------------- launch ----------------
extern "C" void kernel_launch(void* const* d_in, const int* in_sizes, int n_in,
                              void* d_out, int out_size, void* d_ws, size_t ws_size,
                              hipStream_t stream) {
    const void *ev = 0, *emb = 0, *muw = 0;
    const void *w3[3] = {0, 0, 0}, *b3[3] = {0, 0, 0};
    const void *w300[2] = {0, 0};
    const void *b10[3] = {0, 0, 0};
    int n3 = 0, nb3 = 0, n300 = 0, n10 = 0;
    for (int i = 0; i < n_in; ++i) {
        int s = in_sizes[i];
        if      (s == 4104) ev  = d_in[i];
        else if (s == 1180) emb = d_in[i];
        else if (s == 600)  muw = d_in[i];
        else if (s == 3600) { if (n3  < 3) w3[n3++]   = d_in[i]; }
        else if (s == 60)   { if (nb3 < 3) b3[nb3++]  = d_in[i]; }
        else if (s == 300)  { if (n300< 2) w300[n300++]=d_in[i]; }
        else if (s == 10)   { if (n10 < 3) b10[n10++] = d_in[i]; }
    }

    float* ws = (float*)d_ws;
    float* q = ws;
    float* kR = q + 122880;
    float* vR = kR + 122880;
    float* vmupre = vR + 122880;
    float* Wbuf = vmupre + 122880;
    __hip_bfloat16* pbuf = (__hip_bfloat16*)(Wbuf + 371520);

    float* out = (float*)d_out;
    float* out_mu = out;
    float* out_a  = out + 20480;
    float* out_g  = out + 20480 + 10485760;

    ishp_qkv<<<(BB * LL) / 8, 256, 0, stream>>>((const float*)ev, (const float*)emb,
        (const float*)w3[0], (const float*)b3[0],
        (const float*)w3[1], (const float*)b3[1],
        (const float*)w3[2], (const float*)b3[2],
        (const float*)w300[0], (const float*)w300[1],
        q, kR, vR, Wbuf);
    ishp_attn<<<BB * HH * 32, 256, 0, stream>>>(q, kR, vR, pbuf, vmupre);
    ishp_ag<<<(BB * LL * LL) / 256, 256, 0, stream>>>(pbuf, Wbuf,
        (const float*)b10[0], (const float*)b10[1], vmupre,
        (const float*)muw, (const float*)b10[2], out_mu, out_a, out_g);
}